// Round 6
// baseline (574.266 us; speedup 1.0000x reference)
//
#include <hip/hip_runtime.h>
#include <hip/hip_bf16.h>
#include <hip/hip_fp16.h>
#include <math.h>

#define NROW 8192
#define DIM  128
#define ESCALE 8192.0f
#define NPASS 20            // total E-applications; pass 0 fused into buildE
#define SH 64               // stripe height (rows per unit)
#define CW 256              // unit column width
#define NUNITS 2112         // sum over stripes of ceil((NROW - 64s)/256) aligned to 256q

typedef short bf16x8 __attribute__((ext_vector_type(8)));
typedef float f32x4  __attribute__((ext_vector_type(4)));
typedef _Float16 half8 __attribute__((ext_vector_type(8)));

__device__ inline ushort f2bf(float x) { __hip_bfloat16 b = __float2bfloat16(x); return *(ushort*)&b; }
__device__ inline float  bf2f(ushort u) { __hip_bfloat16 b; *(ushort*)&b = u; return __bfloat162float(b); }

// ---------------- init: zero the y-buffer chain, cmax, gpm ----------------
__global__ void init_kernel(float* __restrict__ ybuf, unsigned* __restrict__ cmax,
                            unsigned* __restrict__ gpm) {
    int i = blockIdx.x * 256 + threadIdx.x;     // grid sized exactly NPASS*NROW
    ybuf[i] = 0.0f;
    if (i < NROW) cmax[i] = 0u;
    if (i == 0) gpm[0] = 0u;
}

// ---------------- row normalize + split into bf16 hi/lo ----------------
__global__ void rownorm_kernel(const float* __restrict__ X,
                               ushort* __restrict__ dn_hi, ushort* __restrict__ dn_lo) {
    int row = blockIdx.x;
    int lane = threadIdx.x;            // 64 lanes
    const float2* x2 = reinterpret_cast<const float2*>(X + (size_t)row * DIM);
    float2 v = x2[lane];
    float s = v.x * v.x + v.y * v.y;
    #pragma unroll
    for (int off = 32; off > 0; off >>= 1) s += __shfl_xor(s, off);
    float r = 1.0f / sqrtf(s);
    float a0 = v.x * r, a1 = v.y * r;
    ushort h0 = f2bf(a0), h1 = f2bf(a1);
    ushort l0 = f2bf(a0 - bf2f(h0)), l1 = f2bf(a1 - bf2f(h1));
    ushort2 hv; hv.x = h0; hv.y = h1;
    ushort2 lv; lv.x = l0; lv.y = l1;
    reinterpret_cast<ushort2*>(dn_hi + (size_t)row * DIM)[lane] = hv;
    reinterpret_cast<ushort2*>(dn_lo + (size_t)row * DIM)[lane] = lv;
}

// ------- build E = ESCALE*exp(10*dot-10), diag 0; fused pass-0 row sums -> y0 -------
// Epilogue stages the 128x128 fp16 tile in LDS, then does coalesced half8 stores.
__launch_bounds__(256, 4)
__global__ void buildE_mfma(const ushort* __restrict__ Ahi, const ushort* __restrict__ Alo,
                            _Float16* __restrict__ E, float* __restrict__ y0) {
    __shared__ _Float16 tile[128][132];   // pad 4 fp16: row stride 66 dwords -> +2 bank rotate/row
    int tid = threadIdx.x;
    int w = tid >> 6, l = tid & 63;
    int wm = w >> 1, wn = w & 1;
    int row0 = blockIdx.y * 128 + wm * 64;
    int col0 = blockIdx.x * 128 + wn * 64;
    int lr = l & 15;
    int lk = (l >> 4) * 8;

    f32x4 acc[4][4] = {};
    #pragma unroll
    for (int ks = 0; ks < 4; ++ks) {
        int kb = ks * 32 + lk;
        bf16x8 ah[4], al[4], bh[4], bl[4];
        #pragma unroll
        for (int f = 0; f < 4; ++f) {
            size_t aoff = (size_t)(row0 + f * 16 + lr) * DIM + kb;
            size_t boff = (size_t)(col0 + f * 16 + lr) * DIM + kb;
            ah[f] = *reinterpret_cast<const bf16x8*>(Ahi + aoff);
            al[f] = *reinterpret_cast<const bf16x8*>(Alo + aoff);
            bh[f] = *reinterpret_cast<const bf16x8*>(Ahi + boff);
            bl[f] = *reinterpret_cast<const bf16x8*>(Alo + boff);
        }
        #pragma unroll
        for (int i = 0; i < 4; ++i)
            #pragma unroll
            for (int j = 0; j < 4; ++j) {
                acc[i][j] = __builtin_amdgcn_mfma_f32_16x16x32_bf16(al[i], bh[j], acc[i][j], 0, 0, 0);
                acc[i][j] = __builtin_amdgcn_mfma_f32_16x16x32_bf16(ah[i], bl[j], acc[i][j], 0, 0, 0);
                acc[i][j] = __builtin_amdgcn_mfma_f32_16x16x32_bf16(ah[i], bh[j], acc[i][j], 0, 0, 0);
            }
    }

    int orow = (l >> 4) * 4;
    #pragma unroll
    for (int i = 0; i < 4; ++i) {
        #pragma unroll
        for (int r = 0; r < 4; ++r) {
            int R = wm * 64 + i * 16 + orow + r;       // row within 128-tile
            int gr = blockIdx.y * 128 + R;
            float rsum = 0.0f;
            #pragma unroll
            for (int j = 0; j < 4; ++j) {
                int C = wn * 64 + j * 16 + lr;
                int gc = blockIdx.x * 128 + C;
                float kv = 10.0f * acc[i][j][r] - 10.0f;
                _Float16 eh = (gr == gc) ? (_Float16)0.0f : (_Float16)(__expf(kv) * ESCALE);
                tile[R][C] = eh;
                rsum += (float)eh;
            }
            #pragma unroll
            for (int off = 1; off <= 8; off <<= 1) rsum += __shfl_xor(rsum, off);
            if (lr == 0) atomicAdd(&y0[gr], rsum);
        }
    }
    __syncthreads();

    // coalesced store: thread t writes 16B chunks; 16 lanes = 256B contiguous per row
    int tr = tid >> 4;          // 0..15  (row stepper)
    int tc = tid & 15;          // 16B chunk within row
    size_t gbase = (size_t)(blockIdx.y * 128) * NROW + blockIdx.x * 128;
    #pragma unroll
    for (int it = 0; it < 8; ++it) {
        int R = tr + it * 16;
        half8 v = *reinterpret_cast<const half8*>(&tile[R][tc * 8]);
        *reinterpret_cast<half8*>(E + gbase + (size_t)R * NROW + tc * 8) = v;
    }
}

// ---------------- one Sinkhorn half-pass over upper-triangle units ----------------
// Unit = 64 rows x 256 cols; x = rcp(yprev) on the fly; ynext += E x (row side)
// and += mirror contributions (col side). TRACK: per-col max of x_i*E[i][c] -> cmax.
template <bool TRACK>
__launch_bounds__(256, 4)
__global__ void symv_tri(const _Float16* __restrict__ E, const float* __restrict__ yprev,
                         float* __restrict__ ynext, unsigned* __restrict__ cmax) {
    __shared__ float lds[2048];   // 8 KB, reused across phases
    // ---- unit -> (stripe s, col chunk) ----
    int bid = blockIdx.x;
    int q = 0, cum = 0;
    while (bid >= cum + 4 * (32 - q)) { cum += 4 * (32 - q); ++q; }
    int within = bid - cum;
    int cnt = 32 - q;
    int s = 4 * q + within / cnt;
    int c = within % cnt;
    int row0 = s * SH;
    int col0 = (q + c) * CW;

    int t = threadIdx.x;
    int cg = t & 31;       // 8-col group
    int rg = t >> 5;       // 8-row group

    float xj[8], xi[8];
    {
        float4 ya = *reinterpret_cast<const float4*>(yprev + col0 + 8 * cg);
        float4 yb = *reinterpret_cast<const float4*>(yprev + col0 + 8 * cg + 4);
        xj[0] = __builtin_amdgcn_rcpf(ya.x); xj[1] = __builtin_amdgcn_rcpf(ya.y);
        xj[2] = __builtin_amdgcn_rcpf(ya.z); xj[3] = __builtin_amdgcn_rcpf(ya.w);
        xj[4] = __builtin_amdgcn_rcpf(yb.x); xj[5] = __builtin_amdgcn_rcpf(yb.y);
        xj[6] = __builtin_amdgcn_rcpf(yb.z); xj[7] = __builtin_amdgcn_rcpf(yb.w);
        float4 yc = *reinterpret_cast<const float4*>(yprev + row0 + 8 * rg);
        float4 yd = *reinterpret_cast<const float4*>(yprev + row0 + 8 * rg + 4);
        xi[0] = __builtin_amdgcn_rcpf(yc.x); xi[1] = __builtin_amdgcn_rcpf(yc.y);
        xi[2] = __builtin_amdgcn_rcpf(yc.z); xi[3] = __builtin_amdgcn_rcpf(yc.w);
        xi[4] = __builtin_amdgcn_rcpf(yd.x); xi[5] = __builtin_amdgcn_rcpf(yd.y);
        xi[6] = __builtin_amdgcn_rcpf(yd.z); xi[7] = __builtin_amdgcn_rcpf(yd.w);
    }

    float rowacc[8] = {0, 0, 0, 0, 0, 0, 0, 0};
    float colacc[8] = {0, 0, 0, 0, 0, 0, 0, 0};
    float rowmax[8] = {0, 0, 0, 0, 0, 0, 0, 0};
    float colmax[8] = {0, 0, 0, 0, 0, 0, 0, 0};

    const _Float16* Ebase = E + (size_t)(row0 + 8 * rg) * NROW + col0 + 8 * cg;
    if (col0 >= row0 + SH) {
        // fully right of the diagonal band — no masking
        #pragma unroll
        for (int r = 0; r < 8; ++r) {
            half8 e = *reinterpret_cast<const half8*>(Ebase + (size_t)r * NROW);
            #pragma unroll
            for (int k = 0; k < 8; ++k) {
                float ef = (float)e[k];
                float pr = ef * xj[k];
                float pc = ef * xi[r];
                rowacc[r] += pr;
                colacc[k] += pc;
                if (TRACK) { rowmax[r] = fmaxf(rowmax[r], pr); colmax[k] = fmaxf(colmax[k], pc); }
            }
        }
    } else {
        int grow0 = row0 + 8 * rg;
        #pragma unroll
        for (int r = 0; r < 8; ++r) {
            half8 e = *reinterpret_cast<const half8*>(Ebase + (size_t)r * NROW);
            int grow = grow0 + r;
            #pragma unroll
            for (int k = 0; k < 8; ++k) {
                float ef = (col0 + 8 * cg + k > grow) ? (float)e[k] : 0.0f;
                float pr = ef * xj[k];
                float pc = ef * xi[r];
                rowacc[r] += pr;
                colacc[k] += pc;
                if (TRACK) { rowmax[r] = fmaxf(rowmax[r], pr); colmax[k] = fmaxf(colmax[k], pc); }
            }
        }
    }

    // ---- col sums: reduce over the 8 rg groups ----
    #pragma unroll
    for (int k = 0; k < 8; ++k) lds[rg * 256 + 8 * cg + k] = colacc[k];
    __syncthreads();
    {
        float csum = 0.0f;
        #pragma unroll
        for (int g = 0; g < 8; ++g) csum += lds[g * 256 + t];
        atomicAdd(&ynext[col0 + t], csum);
    }
    __syncthreads();
    // ---- row sums: reduce over the 32 cg groups (rotated layout: conflict-free) ----
    #pragma unroll
    for (int r = 0; r < 8; ++r) {
        int rr = 8 * rg + r;
        lds[rr * 32 + ((cg + rr) & 31)] = rowacc[r];
    }
    __syncthreads();
    if (t < 64) {
        float rsum = 0.0f;
        #pragma unroll
        for (int g = 0; g < 32; ++g) rsum += lds[t * 32 + ((g + t) & 31)];
        atomicAdd(&ynext[row0 + t], rsum);
    }

    if (TRACK) {
        __syncthreads();
        #pragma unroll
        for (int k = 0; k < 8; ++k) lds[rg * 256 + 8 * cg + k] = colmax[k];
        __syncthreads();
        {
            float cmx = 0.0f;
            #pragma unroll
            for (int g = 0; g < 8; ++g) cmx = fmaxf(cmx, lds[g * 256 + t]);
            atomicMax(&cmax[col0 + t], __float_as_uint(cmx));
        }
        __syncthreads();
        #pragma unroll
        for (int r = 0; r < 8; ++r) {
            int rr = 8 * rg + r;
            lds[rr * 32 + ((cg + rr) & 31)] = rowmax[r];
        }
        __syncthreads();
        if (t < 64) {
            float rmx = 0.0f;
            #pragma unroll
            for (int g = 0; g < 32; ++g) rmx = fmaxf(rmx, lds[t * 32 + ((g + t) & 31)]);
            atomicMax(&cmax[row0 + t], __float_as_uint(rmx));
        }
    }
}

// ---------------- a=1/y18, b=1/y19, Pm partials -> gpm ----------------
__global__ void vecfinish(const float* __restrict__ y18, const float* __restrict__ y19,
                          const unsigned* __restrict__ cmax, float* __restrict__ avec,
                          float* __restrict__ bvec, unsigned* __restrict__ gpm) {
    int i = blockIdx.x * 256 + threadIdx.x;
    float a = 1.0f / y18[i];
    float b = 1.0f / y19[i];
    avec[i] = a;
    bvec[i] = b;
    float pv = __uint_as_float(cmax[i]) * b;
    #pragma unroll
    for (int off = 32; off > 0; off >>= 1) pv = fmaxf(pv, __shfl_xor(pv, off));
    __shared__ float lm[4];
    int t = threadIdx.x;
    if ((t & 63) == 0) lm[t >> 6] = pv;
    __syncthreads();
    if (t == 0) atomicMax(gpm, __float_as_uint(fmaxf(fmaxf(lm[0], lm[1]), fmaxf(lm[2], lm[3]))));
}

// ---------------- scp = (1+Pm)/Pm ----------------
__global__ void sc_kernel(const unsigned* __restrict__ gpm, float* __restrict__ scp) {
    float Pm = __uint_as_float(gpm[0]);
    scp[0] = (1.0f + Pm) / Pm;
}

// ---------------- finalize: out = S * P/(1+P), P = a_i E_ij b_j, diag = 1 --------
__launch_bounds__(256)
__global__ void finalize_mult(const _Float16* __restrict__ E, float* __restrict__ out,
                              const float* __restrict__ a, const float* __restrict__ b,
                              const float* __restrict__ scp) {
    float S = scp[0];
    const size_t nt8 = (size_t)NROW * NROW / 8;
    size_t stride = (size_t)gridDim.x * blockDim.x;
    for (size_t e8 = (size_t)blockIdx.x * blockDim.x + threadIdx.x; e8 < nt8; e8 += stride) {
        size_t i = e8 >> 10;                 // 1024 half8 per row
        int j0 = (int)((e8 & 1023) << 3);
        half8 ev = reinterpret_cast<const half8*>(E)[e8];
        float4 b0 = reinterpret_cast<const float4*>(b)[(e8 & 1023) * 2];
        float4 b1 = reinterpret_cast<const float4*>(b)[(e8 & 1023) * 2 + 1];
        float ai = a[i];
        float P[8];
        P[0] = ai * (float)ev[0] * b0.x; P[1] = ai * (float)ev[1] * b0.y;
        P[2] = ai * (float)ev[2] * b0.z; P[3] = ai * (float)ev[3] * b0.w;
        P[4] = ai * (float)ev[4] * b1.x; P[5] = ai * (float)ev[5] * b1.y;
        P[6] = ai * (float)ev[6] * b1.z; P[7] = ai * (float)ev[7] * b1.w;
        float o[8];
        #pragma unroll
        for (int tt = 0; tt < 8; ++tt)
            o[tt] = S * P[tt] * __builtin_amdgcn_rcpf(1.0f + P[tt]);
        if (i >= (size_t)j0 && i < (size_t)j0 + 8) o[i - j0] = 1.0f;
        float4 oa; oa.x = o[0]; oa.y = o[1]; oa.z = o[2]; oa.w = o[3];
        float4 ob; ob.x = o[4]; ob.y = o[5]; ob.z = o[6]; ob.w = o[7];
        reinterpret_cast<float4*>(out)[e8 * 2] = oa;
        reinterpret_cast<float4*>(out)[e8 * 2 + 1] = ob;
    }
}

extern "C" void kernel_launch(void* const* d_in, const int* in_sizes, int n_in,
                              void* d_out, int out_size, void* d_ws, size_t ws_size,
                              hipStream_t stream) {
    const float* X = (const float*)d_in[0];
    float* out = (float*)d_out;
    char* ws = (char*)d_ws;

    size_t off = 0;
    ushort* dn_hi = (ushort*)(ws + off); off += (size_t)NROW * DIM * 2;     // 2 MB
    ushort* dn_lo = (ushort*)(ws + off); off += (size_t)NROW * DIM * 2;     // 2 MB
    float* ybuf   = (float*)(ws + off);  off += (size_t)NPASS * NROW * 4;   // 640 KB
    unsigned* cmax = (unsigned*)(ws + off); off += NROW * 4;
    float* avec   = (float*)(ws + off);  off += NROW * 4;
    float* bvec   = (float*)(ws + off);  off += NROW * 4;
    unsigned* gpm = (unsigned*)(ws + off); off += 64;
    float* scp    = (float*)(ws + off);  off += 64;
    off = (off + 255) & ~(size_t)255;
    _Float16* E = (_Float16*)(ws + off); off += (size_t)NROW * NROW * 2;    // 128 MiB

    init_kernel<<<NPASS * NROW / 256, 256, 0, stream>>>(ybuf, cmax, gpm);
    rownorm_kernel<<<NROW, 64, 0, stream>>>(X, dn_hi, dn_lo);

    dim3 g(NROW / 128, NROW / 128);
    buildE_mfma<<<g, 256, 0, stream>>>(dn_hi, dn_lo, E, ybuf);   // ybuf[0] = E*ones

    for (int p = 1; p < NPASS; ++p) {
        const float* yp = ybuf + (size_t)(p - 1) * NROW;
        float* yn = ybuf + (size_t)p * NROW;
        if (p == NPASS - 1) symv_tri<true ><<<NUNITS, 256, 0, stream>>>(E, yp, yn, cmax);
        else                symv_tri<false><<<NUNITS, 256, 0, stream>>>(E, yp, yn, cmax);
    }

    vecfinish<<<NROW / 256, 256, 0, stream>>>(ybuf + (size_t)(NPASS - 2) * NROW,
                                              ybuf + (size_t)(NPASS - 1) * NROW,
                                              cmax, avec, bvec, gpm);
    sc_kernel<<<1, 1, 0, stream>>>(gpm, scp);
    finalize_mult<<<4096, 256, 0, stream>>>(E, out, avec, bvec, scp);
}